// Round 12
// baseline (81.562 us; speedup 1.0000x reference)
//
#include <hip/hip_runtime.h>

#define NE  5
#define V   25
#define NT  300
#define NC  12
#define CO  64
#define WPB 4
#define GX  38          // 38*4 = 152 wave-tasks; 150 t-pairs (2 idle)

typedef float f4 __attribute__((ext_vector_type(4)));
typedef float f2 __attribute__((ext_vector_type(2)));

// intra-wave LDS ordering: drain this wave's LDS ops + pin compiler ordering.
#define WSYNC() do { asm volatile("s_waitcnt lgkmcnt(0)" ::: "memory"); \
                     __builtin_amdgcn_sched_barrier(0); } while (0)

// select w if bit e of m set, else +0.0
__device__ __forceinline__ float hsel(unsigned m, int e, float w) {
    int s = ((int)(m << (31 - e))) >> 31;
    return __int_as_float(__float_as_int(w) & s);
}

// per-wave scratch float offsets (all arrays scalar-accessed except ST rows)
#define ODV  0      // DV[2][5][25]      = 250
#define OFP  250    // FP[2][15][25]     = 750   (k=3i+c, e)
#define OE_  1000   // edge W[2][5][25]  = 250   (overlaid by ST after P2)
#define OFT  1250   // feat [2][3][25]   = 150   (dead after P1)
#define OB_  1400   // B[2][3][5][25]    = 750   (dead after P2)
#define OST  1000   // ST[50][20] = 1000 overlays OE/FT/B; rows 80B (16B-mult)
#define SCRF 2152   // floats per wave (8608B, 16B multiple)

__global__ __launch_bounds__(256, 4) void hyper_main(
    const float* __restrict__ x,
    const float* __restrict__ h0, const float* __restrict__ h1,
    const float* __restrict__ h2, const float* __restrict__ h3,
    const float* __restrict__ h4,
    const float* __restrict__ wmlp, const float* __restrict__ bmlp,
    float* __restrict__ out)
{
    __shared__ unsigned RM[125];   // row masks [i*25+v] over e
    __shared__ unsigned CM[125];   // col masks [i*25+e] over u
    __shared__ float    DE[125];   // 1/degree_e
    __shared__ __align__(16) float WPs[32*32];  // [o2][2k interleaved w + 2 bias]
    __shared__ __align__(16) float SCR[WPB][SCRF];

    const int tid  = threadIdx.x;
    const int lane = tid & 63;
    const int wid  = tid >> 6;
    const int b    = blockIdx.y;

    // ---- block init ----
    if (tid < 125) {
        int i = tid / 25, v = tid % 25;
        const float* hp = (i==0)?h0:(i==1)?h1:(i==2)?h2:(i==3)?h3:h4;
        unsigned m = 0;
        for (int e = 0; e < V; ++e) if (hp[v*V + e] != 0.f) m |= (1u << e);
        RM[tid] = m;
    } else if (tid < 250) {
        int idx = tid - 125, i = idx / 25, e = idx % 25;
        const float* hp = (i==0)?h0:(i==1)?h1:(i==2)?h2:(i==3)?h3:h4;
        unsigned m = 0; float s = 0.f;
        for (int u = 0; u < V; ++u) {
            float hv = hp[u*V + e];
            s += hv;
            if (hv != 0.f) m |= (1u << u);
        }
        CM[idx] = m;
        DE[idx] = (s != 0.f) ? __fdiv_rn(1.f, s) : 0.f;
    }
    // stage MLP weights interleaved: WPs[o2*32 + j]:
    //   j<30: w[2*o2 + (j&1)][j>>1];  j=30,31: bias[2*o2], bias[2*o2+1]
    for (int q = tid; q < 1024; q += 256) {
        int o2 = q >> 5, j = q & 31;
        WPs[q] = (j < 30) ? wmlp[(2*o2 + (j & 1))*15 + (j >> 1)]
                          : bmlp[2*o2 + (j - 30)];
    }
    __syncthreads();   // only block-wide barrier

    const int pp = blockIdx.x * WPB + wid;   // one t-pair per wave
    if (pp >= NT/2) return;

    float* S = SCR[wid];

    // ---- prologue: load BOTH t's 8 channels x 25 (400 items, 7 rounds) ----
    float pf[7]; int lo[7];
    #pragma unroll
    for (int r = 0; r < 7; ++r) {
        int q  = r*64 + lane;
        int qq = (q < 400) ? q : 0;
        int tt = qq / 200, rr = qq % 200, ch = rr / 25, e = rr % 25;
        int xc = (ch < 5) ? (ch + 6 + (ch >= 2 ? 1 : 0)) : (ch - 5);
        lo[r] = ((ch < 5) ? (OE_ + tt*125 + ch*25) : (OFT + tt*75 + (ch-5)*25)) + e;
        pf[r] = x[((size_t)(b*NC + xc)*NT + (2*pp + tt))*V + e];
    }
    #pragma unroll
    for (int r = 0; r < 6; ++r) S[lo[r]] = pf[r];
    if (lane < 16) S[lo[6]] = pf[6];
    WSYNC();

    // ---- P1: dv via mod-4 class bit-loops (bit-exact numpy association:
    // skipped terms are +0.0 adds = bitwise identity) + B, both t's ----
    #pragma unroll
    for (int r = 0; r < 4; ++r) {
        int idx = r*64 + lane;
        if (idx < 250) {
            int tt  = (idx >= 125) ? 1 : 0;
            int rem = idx - (tt ? 125 : 0);
            int i = rem / 25, v = rem % 25;
            unsigned m = RM[rem];
            const float* wi = S + OE_ + tt*125 + i*25;
            float L0 = 0.f, L1 = 0.f, L2 = 0.f, L3 = 0.f;
            unsigned mm;
            mm = m & 0x00111111u;
            while (mm) { int e = __builtin_ctz(mm); mm &= mm-1; L0 = __fadd_rn(L0, wi[e]); }
            mm = m & 0x00222222u;
            while (mm) { int e = __builtin_ctz(mm); mm &= mm-1; L1 = __fadd_rn(L1, wi[e]); }
            mm = m & 0x00444444u;
            while (mm) { int e = __builtin_ctz(mm); mm &= mm-1; L2 = __fadd_rn(L2, wi[e]); }
            mm = m & 0x00888888u;
            while (mm) { int e = __builtin_ctz(mm); mm &= mm-1; L3 = __fadd_rn(L3, wi[e]); }
            float s = __fadd_rn(__fadd_rn(L0, L1), __fadd_rn(L2, L3));
            s = __fadd_rn(s, hsel(m, 24, wi[24]));
            float dvv = (s > 0.f) ? (float)(1.0 / sqrt((double)s)) : 0.f;
            S[ODV + tt*125 + i*25 + v] = dvv;
            float f0  = S[OFT + tt*75 +  0 + v];
            float f1  = S[OFT + tt*75 + 25 + v];
            float f2v = S[OFT + tt*75 + 50 + v];
            S[OB_ + tt*375 +   0 + i*25 + v] = dvv * f0;
            S[OB_ + tt*375 + 125 + i*25 + v] = dvv * f1;
            S[OB_ + tt*375 + 250 + i*25 + v] = dvv * f2v;
        }
    }
    WSYNC();

    // ---- P2: FP[tt][3i+c][e] = (w[e]*de[e]) * sum_u h[u,e]*B[tt][c][i][u] ----
    #pragma unroll
    for (int r = 0; r < 4; ++r) {
        int idx = r*64 + lane;
        if (idx < 250) {
            int tt  = (idx >= 125) ? 1 : 0;
            int rem = idx - (tt ? 125 : 0);
            int i = rem / 25, e = rem % 25;
            unsigned m = CM[rem];
            const float* bp = S + OB_ + tt*375 + i*25;
            float a0 = 0.f, a1 = 0.f, a2 = 0.f;
            while (m) {
                int u = __builtin_ctz(m); m &= m - 1;
                a0 += bp[u]; a1 += bp[125 + u]; a2 += bp[250 + u];
            }
            float gg = S[OE_ + tt*125 + i*25 + e] * DE[rem];
            S[OFP + tt*375 + (i*3+0)*25 + e] = a0 * gg;
            S[OFP + tt*375 + (i*3+1)*25 + e] = a1 * gg;
            S[OFP + tt*375 + (i*3+2)*25 + e] = a2 * gg;
        }
    }
    WSYNC();

    // ---- P3: ST[tt*25+v][3i+c] = dv * sum_e h[v,e]*FP[tt][3i+c][e] ----
    // (ST overlays OE/FT/B, all dead after P2)
    #pragma unroll
    for (int r = 0; r < 4; ++r) {
        int idx = r*64 + lane;
        if (idx < 250) {
            int tt  = (idx >= 125) ? 1 : 0;
            int rem = idx - (tt ? 125 : 0);
            int i = rem / 25, v = rem % 25;
            unsigned m = RM[rem];
            const float* fp = S + OFP + tt*375 + i*3*25;
            float a0 = 0.f, a1 = 0.f, a2 = 0.f;
            while (m) {
                int e = __builtin_ctz(m); m &= m - 1;
                a0 += fp[e]; a1 += fp[25 + e]; a2 += fp[50 + e];
            }
            float dd = S[ODV + tt*125 + i*25 + v];
            float* st = S + OST + (tt*25 + v)*20 + i*3;
            st[0] = a0 * dd; st[1] = a1 * dd; st[2] = a2 * dd;
        }
    }
    WSYNC();

    // ---- P4: MLP + relu; weights via broadcast LDS b128, nt stores ----
    if (lane < 50) {
        const float* st = S + OST + lane*20;
        f4 s0 = *(const f4*)(st+0), s1 = *(const f4*)(st+4),
           s2 = *(const f4*)(st+8), s3 = *(const f4*)(st+12);
        s3.w = 0.f;
        float* ob = out + (size_t)b*CO*7500 + (size_t)pp*50 + lane;
        #pragma unroll 2
        for (int o2 = 0; o2 < 32; ++o2) {
            const float* wp = WPs + o2*32;
            f4 c0 = *(const f4*)(wp+ 0), c1 = *(const f4*)(wp+ 4),
               c2 = *(const f4*)(wp+ 8), c3 = *(const f4*)(wp+12),
               c4 = *(const f4*)(wp+16), c5 = *(const f4*)(wp+20),
               c6 = *(const f4*)(wp+24), c7 = *(const f4*)(wp+28);
            f2 a = (f2){c7.z, c7.w};                 // bias pair
            a += (f2){c0.x, c0.y} * s0.x;            // k=0
            a += (f2){c0.z, c0.w} * s0.y;            // k=1
            a += (f2){c1.x, c1.y} * s0.z;
            a += (f2){c1.z, c1.w} * s0.w;
            a += (f2){c2.x, c2.y} * s1.x;
            a += (f2){c2.z, c2.w} * s1.y;
            a += (f2){c3.x, c3.y} * s1.z;
            a += (f2){c3.z, c3.w} * s1.w;
            a += (f2){c4.x, c4.y} * s2.x;
            a += (f2){c4.z, c4.w} * s2.y;
            a += (f2){c5.x, c5.y} * s2.z;
            a += (f2){c5.z, c5.w} * s2.w;
            a += (f2){c6.x, c6.y} * s3.x;
            a += (f2){c6.z, c6.w} * s3.y;
            a += (f2){c7.x, c7.y} * s3.z;            // k=14
            __builtin_nontemporal_store(fmaxf(a.x, 0.f), ob + (size_t)(2*o2  )*7500);
            __builtin_nontemporal_store(fmaxf(a.y, 0.f), ob + (size_t)(2*o2+1)*7500);
        }
    }
}

extern "C" void kernel_launch(void* const* d_in, const int* in_sizes, int n_in,
                              void* d_out, int out_size, void* d_ws, size_t ws_size,
                              hipStream_t stream) {
    const float* x    = (const float*)d_in[0];
    const float* h0   = (const float*)d_in[1];
    const float* h1   = (const float*)d_in[2];
    const float* h2   = (const float*)d_in[3];
    const float* h3   = (const float*)d_in[4];
    const float* h4   = (const float*)d_in[5];
    const float* wmlp = (const float*)d_in[6];
    const float* bmlp = (const float*)d_in[7];
    float* out = (float*)d_out;

    hyper_main<<<dim3(GX, 64, 1), dim3(256,1,1), 0, stream>>>(
        x, h0, h1, h2, h3, h4, wmlp, bmlp, out);
}